// Round 10
// baseline (289.500 us; speedup 1.0000x reference)
//
#include <hip/hip_runtime.h>
#include <hip/hip_bf16.h>
#include <cstdint>

// GraphSAGE 2-layer, bf16 features + fp32 accumulate, MFMA GEMMs.
// Layer1: h   = relu([mean_agg(x) | x] @ [W1_l; W1_r] + b1)   (K=256 MFMA GEMM)
// Layer2: out = mean_agg(h @ W2_l) + h @ W2_r + b2            (agg commutes w/ linear)
// R20 pipeline (6 dispatches):
//   memset(bucket_pos|dhist|dcur) -> fused_front -> pass3 (+degree hist)
//   -> build_perm (counting-sort nodes by degree -> nodeperm)
//   -> agg16_gemm (16-wave block over DEGREE-BALANCED nodes; barrier handoff)
//   -> agg64 (dual-node, in-place epilogue on out)
// R19 DIAGNOSIS (99.6us, gather 1.9TB/s vs 3.0 standalone): __syncthreads
// waits for max of 16 Poisson(16) degrees ~= 26 vs mean 16 -> ~65% gather
// inflation (59*1.65=97 ~ 99.6 observed). R20: counting-sort by degree so
// each block's 16 nodes have equal degree -> barrier straggler ~= 0. Row
// permutation is free for gemm (writes are per-row contiguous; agg64 is
// order-independent). nodeperm carved from unused z2-region tail.
// R18 FALSIFIED (2880us): per-block __threadfence = L2 wbl2/inv flush;
// NEVER per-block device-scope fences. R13 FALSIFIED: per-bucket serial agg
// (kills TLP). R14 standalone 16row gemm, R11 shfl-bcast, R10 dim-slab,
// R15 range-split all FALSIFIED. fdot2_f32_bf16 WRONG on gfx950 (R6).
// LEDGER: agg128 59=floor (177.8MB @3.5TB/s fabric); agg64 ~41 (R17 WIN);
// gemm ~33 (from R19 algebra); front+pass3 + ~30 harness dispatches opaque.

typedef __bf16 bf16x8 __attribute__((ext_vector_type(8)));
typedef float f32x4 __attribute__((ext_vector_type(4)));
typedef float f32x2 __attribute__((ext_vector_type(2)));

#define MAXBUCK 800   // >= ceil(102400/128)
#define CAP 2560      // per-bucket edge capacity; mean 2046, sigma ~45
#define MAXEPT 16
#define P2B 512       // pass2 blocks
#define P2E (MAXEPT * 256)   // staging capacity (4096; ept=13 uses 3328)
#define HSTRIDE 136   // bf16 elems per scratch row (272B, 16B-aligned)
#define NBIN 64       // degree bins for balance sort (deg clamped to 63)

__device__ __forceinline__ unsigned short f2bf(float f) {
    union { float f; unsigned int u; } v; v.f = f;
    unsigned int u = v.u;
    unsigned int r = ((u >> 16) & 1u) + 0x7fffu;
    return (unsigned short)((u + r) >> 16);
}

// unpack uint (2 bf16) -> f32x2 {lo, hi}
__device__ __forceinline__ f32x2 up2(unsigned int u) {
    uint2 t; t.x = u << 16; t.y = u & 0xffff0000u;
    return __builtin_bit_cast(f32x2, t);
}
__device__ __forceinline__ void accp(const uint4& v, f32x2* a) {
    a[0] += up2(v.x);
    a[1] += up2(v.y);
    a[2] += up2(v.z);
    a[3] += up2(v.w);
}
__device__ __forceinline__ void accpw(const uint4& v, float w, f32x2* a) {
    a[0] += up2(v.x) * w;
    a[1] += up2(v.y) * w;
    a[2] += up2(v.z) * w;
    a[3] += up2(v.w) * w;
}

__device__ __forceinline__ int edge_val(const int* ei32, const long long* ei64,
                                        int is64, size_t idx) {
    return is64 ? (int)ei64[idx] : ei32[idx];
}

// ---------------- FUSED FRONT: pass2 sorted-partition | cvt | w frags ------
__global__ __launch_bounds__(256) void fused_front(const float* __restrict__ x,
                                                   unsigned short* __restrict__ xb,
                                                   long long n8, int ncvt,
                                                   const float* __restrict__ W1l,
                                                   const float* __restrict__ W1r,
                                                   uint4* __restrict__ w1frag,
                                                   const float* __restrict__ W2l,
                                                   const float* __restrict__ W2r,
                                                   uint4* __restrict__ w2frag,
                                                   const int* __restrict__ ei32,
                                                   const long long* __restrict__ ei64,
                                                   int E, int ept, int nbuck,
                                                   int n_nodes,
                                                   int* __restrict__ bucket_pos,
                                                   unsigned* __restrict__ ebuf) {
    __shared__ int lhist[MAXBUCK];
    __shared__ int lexcl[MAXBUCK];
    __shared__ int gbase[MAXBUCK];
    __shared__ int part[256];
    __shared__ unsigned estage[P2E];
    __shared__ unsigned short bstage[P2E];
    int b = blockIdx.x;
    int t = threadIdx.x;
    if (b < P2B) {
        // ---- pass2 role: partition edges into padded buckets, sorted ----
        for (int i = t; i < nbuck; i += 256) lhist[i] = 0;
        __syncthreads();
        int is64;
        {   // self-detect: 8 uniform loads; garbage-as-int64 fails bounds
            int ok = 1;
            for (int i = 0; i < 8; ++i) {
                long long v = ei64[i];
                if (v < 0 || v >= n_nodes) ok = 0;
            }
            is64 = ok;
        }
        int base_e = b * (ept * 256);
        unsigned ed[MAXEPT];
        int bidx[MAXEPT];
        int slot[MAXEPT];
#pragma unroll 4
        for (int i = 0; i < ept; ++i) {
            int e = base_e + i * 256 + t;
            if (e < E) {
                int s = edge_val(ei32, ei64, is64, (size_t)e);
                int d = edge_val(ei32, ei64, is64, (size_t)E + e);
                ed[i] = ((unsigned)s << 7) | (unsigned)(d & 127);
                bidx[i] = d >> 7;
                slot[i] = atomicAdd(&lhist[d >> 7], 1);
            } else {
                slot[i] = -1;
            }
        }
        __syncthreads();
        // block-local exclusive scan of lhist[0..nbuck) (4 buckets/thread)
        int base4 = t * 4;
        int c0 = (base4 + 0 < nbuck) ? lhist[base4 + 0] : 0;
        int c1 = (base4 + 1 < nbuck) ? lhist[base4 + 1] : 0;
        int c2 = (base4 + 2 < nbuck) ? lhist[base4 + 2] : 0;
        int c3 = (base4 + 3 < nbuck) ? lhist[base4 + 3] : 0;
        int lsum = c0 + c1 + c2 + c3;
        part[t] = lsum;
        __syncthreads();
        for (int o = 1; o < 256; o <<= 1) {
            int xv = 0;
            if (t >= o) xv = part[t - o];
            __syncthreads();
            if (t >= o) part[t] += xv;
            __syncthreads();
        }
        {
            int run = part[t] - lsum;
            if (base4 + 0 < nbuck) { lexcl[base4 + 0] = run; run += c0; }
            if (base4 + 1 < nbuck) { lexcl[base4 + 1] = run; run += c1; }
            if (base4 + 2 < nbuck) { lexcl[base4 + 2] = run; run += c2; }
            if (base4 + 3 < nbuck) { lexcl[base4 + 3] = run; run += c3; }
        }
        // global reservations (independent of scan results)
        for (int i = t; i < nbuck; i += 256) {
            int c = lhist[i];
            gbase[i] = c ? atomicAdd(&bucket_pos[i], c) : 0;
        }
        __syncthreads();
        // stage edges into LDS, bucket-sorted
#pragma unroll 4
        for (int i = 0; i < ept; ++i) {
            if (slot[i] >= 0) {
                int pos = lexcl[bidx[i]] + slot[i];
                estage[pos] = ed[i];
                bstage[pos] = (unsigned short)bidx[i];
            }
        }
        __syncthreads();
        // emit: consecutive lanes -> same-bucket runs (coalesced-ish writes)
        int m_blk = E - base_e;
        if (m_blk < 0) m_blk = 0;
        if (m_blk > ept * 256) m_blk = ept * 256;
        for (int s = t; s < m_blk; s += 256) {
            int bb = bstage[s];
            int pos = gbase[bb] + (s - lexcl[bb]);
            if (pos < CAP) ebuf[(size_t)bb * CAP + pos] = estage[s];
        }
        return;
    }
    int cb = b - P2B;
    if (cb < ncvt) {
        // ---- cvt role: x (f32) -> xb (bf16), 16B out per thread ----
        long long i = (long long)cb * 256 + t;
        if (i >= n8) return;
        const float4* p = (const float4*)(x + i * 8);
        float4 a = p[0], c = p[1];
        uint4 o;
        o.x = (unsigned)f2bf(a.x) | ((unsigned)f2bf(a.y) << 16);
        o.y = (unsigned)f2bf(a.z) | ((unsigned)f2bf(a.w) << 16);
        o.z = (unsigned)f2bf(c.x) | ((unsigned)f2bf(c.y) << 16);
        o.w = (unsigned)f2bf(c.z) | ((unsigned)f2bf(c.w) << 16);
        ((uint4*)(xb))[i] = o;
        return;
    }
    if (cb < ncvt + 16) {   // W1 frags: Wcat[256][128] = [W1_l; W1_r], 64 frags
        int tid = (cb - ncvt) * 256 + t;   // 4096
        int fi = tid >> 6, lane = tid & 63;
        int ct = fi >> 3, ks = fi & 7;
        int k0 = ks * 32 + (lane >> 4) * 8;
        int n = ct * 16 + (lane & 15);
        unsigned short e[8];
#pragma unroll
        for (int j = 0; j < 8; ++j) {
            int k = k0 + j;
            float v = (k < 128) ? W1l[k * 128 + n] : W1r[(k - 128) * 128 + n];
            e[j] = f2bf(v);
        }
        uint4 o;
        o.x = (unsigned)e[0] | ((unsigned)e[1] << 16);
        o.y = (unsigned)e[2] | ((unsigned)e[3] << 16);
        o.z = (unsigned)e[4] | ((unsigned)e[5] << 16);
        o.w = (unsigned)e[6] | ((unsigned)e[7] << 16);
        w1frag[tid] = o;
        return;
    }
    // W2 frags: Wcat2[128][128] = [W2_l | W2_r], 32 frags
    int tid = (cb - ncvt - 16) * 256 + t;   // 2048
    if (tid >= 2048) return;
    int fi = tid >> 6, lane = tid & 63;
    int ct = fi >> 2, ks = fi & 3;
    int k0 = ks * 32 + (lane >> 4) * 8;
    int n = ct * 16 + (lane & 15);
    unsigned short e[8];
#pragma unroll
    for (int j = 0; j < 8; ++j) {
        int k = k0 + j;
        float v = (n < 64) ? W2l[k * 64 + n] : W2r[k * 64 + (n - 64)];
        e[j] = f2bf(v);
    }
    uint4 o;
    o.x = (unsigned)e[0] | ((unsigned)e[1] << 16);
    o.y = (unsigned)e[2] | ((unsigned)e[3] << 16);
    o.z = (unsigned)e[4] | ((unsigned)e[5] << 16);
    o.w = (unsigned)e[6] | ((unsigned)e[7] << 16);
    w2frag[tid] = o;
}

// pass3: one block per bucket; counts, scan, startcnt + csr + degree hist
__global__ __launch_bounds__(256) void pass3_finalize(const unsigned* __restrict__ ebuf,
                                                      const int* __restrict__ bucket_pos,
                                                      int nbuck, int N,
                                                      int2* __restrict__ startcnt,
                                                      int* __restrict__ csr,
                                                      int* __restrict__ dhist) {
    __shared__ int lcnt[128];
    __shared__ int lexcl[128];
    __shared__ int sc[128];
    __shared__ int ldh[NBIN];
    int b = blockIdx.x;
    int t = threadIdx.x;
    int d0 = b << 7;
    int nb = N - d0; if (nb > 128) nb = 128;
    int m = bucket_pos[b]; if (m > CAP) m = CAP;
    const unsigned* eb = ebuf + (size_t)b * CAP;

    if (t < 128) lcnt[t] = 0;
    if (t < NBIN) ldh[t] = 0;
    __syncthreads();
    for (int j = t; j < m; j += 256) {
        atomicAdd(&lcnt[eb[j] & 127u], 1);
    }
    __syncthreads();
    int v = 0;
    if (t < 128) { v = lcnt[t]; sc[t] = v; }
    __syncthreads();
    for (int o = 1; o < 128; o <<= 1) {
        int x = 0;
        if (t < 128 && t >= o) x = sc[t - o];
        __syncthreads();
        if (t < 128 && t >= o) sc[t] += x;
        __syncthreads();
    }
    if (t < 128) {
        int excl = sc[t] - v;
        lexcl[t] = excl;
        if (t < nb) {
            startcnt[d0 + t] = make_int2(b * CAP + excl, v);
            atomicAdd(&ldh[(v > 63) ? 63 : v], 1);
        }
        lcnt[t] = 0;   // reuse as running pos
    }
    __syncthreads();
    if (t < NBIN) {
        int c = ldh[t];
        if (c) atomicAdd(&dhist[t], c);
    }
    for (int j = t; j < m; j += 256) {
        unsigned ed = eb[j];
        int li = (int)(ed & 127u);
        int slot = atomicAdd(&lcnt[li], 1);
        csr[b * CAP + lexcl[li] + slot] = (int)(ed >> 7);
    }
}

// build_perm: counting-sort node ids by degree bin -> nodeperm.
// Each block: local 64-bin hist over 1024 nodes, parallel scan of global
// dhist (redundant per block), per-bin reservation via dcur, scatter.
__global__ __launch_bounds__(256) void build_perm(const int2* __restrict__ startcnt,
                                                  const int* __restrict__ dhist,
                                                  int* __restrict__ dcur,
                                                  int* __restrict__ nodeperm,
                                                  int N) {
    __shared__ int lh[NBIN];
    __shared__ int gb[NBIN];
    __shared__ int sc64[NBIN];
    int t = threadIdx.x;
    if (t < NBIN) lh[t] = 0;
    __syncthreads();
    int n0 = blockIdx.x * 1024;
    int dloc[4], sloc[4];
#pragma unroll
    for (int i = 0; i < 4; ++i) {
        int n = n0 + i * 256 + t;
        if (n < N) {
            int d = startcnt[n].y; if (d > 63) d = 63;
            dloc[i] = d;
            sloc[i] = atomicAdd(&lh[d], 1);
        } else sloc[i] = -1;
    }
    int dh0 = 0;
    if (t < NBIN) { dh0 = dhist[t]; sc64[t] = dh0; }
    __syncthreads();
    for (int o = 1; o < NBIN; o <<= 1) {
        int xv = 0;
        if (t < NBIN && t >= o) xv = sc64[t - o];
        __syncthreads();
        if (t < NBIN && t >= o) sc64[t] += xv;
        __syncthreads();
    }
    if (t < NBIN) {
        int dbase = sc64[t] - dh0;   // exclusive global prefix
        int c = lh[t];
        gb[t] = dbase + (c ? atomicAdd(&dcur[t], c) : 0);
    }
    __syncthreads();
#pragma unroll
    for (int i = 0; i < 4; ++i) {
        if (sloc[i] >= 0) {
            int n = n0 + i * 256 + t;
            nodeperm[gb[dloc[i]] + sloc[i]] = n;
        }
    }
}

// ------- MERGED: 16-wave block = 16-node agg + in-block gemm1+gemm2 -------
// Nodes come from nodeperm (degree-balanced): all 16 waves finish the gather
// near-simultaneously -> barrier straggler ~0. Mean rows -> LDS only.
__global__ __launch_bounds__(1024, 8) void agg16_gemm(const unsigned short* __restrict__ Xb,
                                                      const int2* __restrict__ startcnt,
                                                      const int* __restrict__ csr,
                                                      const int* __restrict__ nodeperm,
                                                      const uint4* __restrict__ w1frag,
                                                      const uint4* __restrict__ w2frag,
                                                      const float* __restrict__ b1,
                                                      const float* __restrict__ b2,
                                                      unsigned short* __restrict__ z2,
                                                      float* __restrict__ outw2,
                                                      int n_nodes) {
    __shared__ unsigned short ms[16 * HSTRIDE];   // mean rows (bf16)
    __shared__ unsigned short xs[16 * HSTRIDE];   // x rows (bf16)
    __shared__ unsigned short hsb[16 * HSTRIDE];  // h rows (bf16)
    __shared__ int pn[16];                        // permuted node ids
    const int t = threadIdx.x;
    const int wid = t >> 6;            // 0..15
    const int lane = t & 63;
    const int quad = lane >> 4, l16 = lane & 15;

    // ---- agg phase: one (permuted) node per wave ----
    {
        int slot = blockIdx.x * 16 + wid;
        if (slot >= n_nodes) slot = n_nodes - 1;   // tail safety (N%16==0 here)
        int node = nodeperm[slot];
        if (lane == 0) pn[wid] = node;
        // stage this node's x row into LDS
        if (quad == 0) {
            *(uint4*)(xs + wid * HSTRIDE + l16 * 8) =
                ((const uint4*)(Xb + (size_t)node * 128))[l16];
        }
        int2 sc2 = startcnt[node];
        int s0 = sc2.x, deg = sc2.y, s1 = s0 + deg;
        f32x2 A0[4], A1[4];
#pragma unroll
        for (int k = 0; k < 4; ++k) { A0[k] = (f32x2){0.f, 0.f}; A1[k] = (f32x2){0.f, 0.f}; }
        int j = s0;
        for (; j + 8 <= s1; j += 8) {
            int p0 = csr[j + quad];
            int p1 = csr[j + 4 + quad];
            uint4 v0 = ((const uint4*)(Xb + (size_t)p0 * 128))[l16];
            uint4 v1 = ((const uint4*)(Xb + (size_t)p1 * 128))[l16];
            accp(v0, A0);
            accp(v1, A1);
        }
        if (j + 4 <= s1) {
            int p = csr[j + quad];
            uint4 v = ((const uint4*)(Xb + (size_t)p * 128))[l16];
            accp(v, A0);
            j += 4;
        }
        if (j < s1) {  // masked tail, 1..3 edges
            int jj = j + quad;
            int p = csr[(jj < s1) ? jj : (s1 - 1)];
            float w = (jj < s1) ? 1.0f : 0.0f;
            uint4 v = ((const uint4*)(Xb + (size_t)p * 128))[l16];
            accpw(v, w, A1);
        }
        float r[8];
#pragma unroll
        for (int k = 0; k < 4; ++k) {
            f32x2 s = A0[k] + A1[k];
            r[2 * k] = s.x;
            r[2 * k + 1] = s.y;
        }
#pragma unroll
        for (int k = 0; k < 8; ++k) r[k] += __shfl(r[k], lane ^ 16);
#pragma unroll
        for (int k = 0; k < 8; ++k) r[k] += __shfl(r[k], lane ^ 32);
        float inv = (deg > 0) ? 1.0f / (float)deg : 0.0f;
        if (quad == 0) {
            uint4 o;
            o.x = (unsigned)f2bf(r[0] * inv) | ((unsigned)f2bf(r[1] * inv) << 16);
            o.y = (unsigned)f2bf(r[2] * inv) | ((unsigned)f2bf(r[3] * inv) << 16);
            o.z = (unsigned)f2bf(r[4] * inv) | ((unsigned)f2bf(r[5] * inv) << 16);
            o.w = (unsigned)f2bf(r[6] * inv) | ((unsigned)f2bf(r[7] * inv) << 16);
            *(uint4*)(ms + wid * HSTRIDE + l16 * 8) = o;
        }
    }
    __syncthreads();   // means + x rows + pn visible block-wide

    // ---- gemm1: waves 0-7, one ct each; A = [mean | x] from LDS ----
    if (wid < 8) {
        bf16x8 af[8];
#pragma unroll
        for (int ks = 0; ks < 4; ++ks) {
            af[ks] = __builtin_bit_cast(bf16x8,
                *(const uint4*)(ms + l16 * HSTRIDE + ks * 32 + quad * 8));
            af[ks + 4] = __builtin_bit_cast(bf16x8,
                *(const uint4*)(xs + l16 * HSTRIDE + ks * 32 + quad * 8));
        }
        const uint4* w1p = w1frag + lane;
        f32x4 a0 = (f32x4){0.f, 0.f, 0.f, 0.f};
#pragma unroll
        for (int ks = 0; ks < 8; ++ks) {
            uint4 wc = w1p[(wid * 8 + ks) * 64];
            a0 = __builtin_amdgcn_mfma_f32_16x16x32_bf16(
                af[ks], __builtin_bit_cast(bf16x8, wc), a0, 0, 0, 0);
        }
        int col = wid * 16 + l16;
        float bb = b1[col];
#pragma unroll
        for (int r = 0; r < 4; ++r) {
            hsb[(quad * 4 + r) * HSTRIDE + col] = f2bf(fmaxf(a0[r] + bb, 0.f));
        }
    }
    __syncthreads();   // h complete

    // ---- gemm2: waves 8-15, one ct each; A = h (transpose-read LDS) ----
    if (wid >= 8) {
        int ct = wid - 8;
        bf16x8 af2[4];
#pragma unroll
        for (int ks = 0; ks < 4; ++ks) {
            af2[ks] = __builtin_bit_cast(bf16x8,
                *(const uint4*)(hsb + l16 * HSTRIDE + ks * 32 + quad * 8));
        }
        const uint4* w2p = w2frag + lane;
        f32x4 a0 = (f32x4){0.f, 0.f, 0.f, 0.f};
#pragma unroll
        for (int ks = 0; ks < 4; ++ks) {
            uint4 wc2 = w2p[(ct * 4 + ks) * 64];
            a0 = __builtin_amdgcn_mfma_f32_16x16x32_bf16(
                af2[ks], __builtin_bit_cast(bf16x8, wc2), a0, 0, 0, 0);
        }
        int col = ct * 16 + l16;
#pragma unroll
        for (int r = 0; r < 4; ++r) {
            int orow = pn[quad * 4 + r];   // permuted output row
            if (col < 64) {
                z2[(size_t)orow * 64 + col] = f2bf(a0[r]);
            } else {
                outw2[(size_t)orow * 64 + (col - 64)] = a0[r] + b2[col - 64];
            }
        }
    }
}

// ---------------- mean aggregation, D=64 bf16, DUAL-NODE waves, +out -------
__global__ __launch_bounds__(256) void agg_mean64_bf_ep(const unsigned short* __restrict__ Zb,
                                                        const int2* __restrict__ startcnt,
                                                        const int* __restrict__ csr,
                                                        float* __restrict__ out,
                                                        int n_nodes) {
    int node = blockIdx.x * 8 + (threadIdx.x >> 5);   // 8 nodes per block
    if (node >= n_nodes) return;
    int lane = threadIdx.x & 63;
    int hl = lane & 31;          // lane within half
    int oct4 = hl >> 3;          // 0..3
    int l8 = hl & 7;
    int2 sc2 = startcnt[node];
    int s0 = sc2.x, deg = sc2.y, s1 = s0 + deg;
    f32x2 A0[4], A1[4];
#pragma unroll
    for (int k = 0; k < 4; ++k) { A0[k] = (f32x2){0.f, 0.f}; A1[k] = (f32x2){0.f, 0.f}; }
    int j = s0;
    for (; j + 8 <= s1; j += 8) {
        int p0 = csr[j + oct4];
        int p1 = csr[j + 4 + oct4];
        uint4 v0 = ((const uint4*)(Zb + (size_t)p0 * 64))[l8];
        uint4 v1 = ((const uint4*)(Zb + (size_t)p1 * 64))[l8];
        accp(v0, A0);
        accp(v1, A1);
    }
    if (j + 4 <= s1) {
        int p = csr[j + oct4];
        uint4 v = ((const uint4*)(Zb + (size_t)p * 64))[l8];
        accp(v, A0);
        j += 4;
    }
    if (j < s1) {  // masked tail, 1..3 edges
        int jj = j + oct4;
        int p = csr[(jj < s1) ? jj : (s1 - 1)];
        float w = (jj < s1) ? 1.0f : 0.0f;
        uint4 v = ((const uint4*)(Zb + (size_t)p * 64))[l8];
        accpw(v, w, A1);
    }
    float r[8];
#pragma unroll
    for (int k = 0; k < 4; ++k) {
        f32x2 s = A0[k] + A1[k];
        r[2 * k] = s.x;
        r[2 * k + 1] = s.y;
    }
    // reduce across 4 octs within each 32-lane half (xor 8, 16 stay in-half)
#pragma unroll
    for (int k = 0; k < 8; ++k) r[k] += __shfl(r[k], lane ^ 8);
#pragma unroll
    for (int k = 0; k < 8; ++k) r[k] += __shfl(r[k], lane ^ 16);
    float inv = (deg > 0) ? 1.0f / (float)deg : 0.0f;
    if (oct4 == 0) {
        float4* op = (float4*)(out + (size_t)node * 64 + l8 * 8);
        float4 w0 = op[0], w1 = op[1];
        float4 o0, o1;
        o0.x = r[0] * inv + w0.x; o0.y = r[1] * inv + w0.y;
        o0.z = r[2] * inv + w0.z; o0.w = r[3] * inv + w0.w;
        o1.x = r[4] * inv + w1.x; o1.y = r[5] * inv + w1.y;
        o1.z = r[6] * inv + w1.z; o1.w = r[7] * inv + w1.w;
        op[0] = o0; op[1] = o1;
    }
}

extern "C" void kernel_launch(void* const* d_in, const int* in_sizes, int n_in,
                              void* d_out, int out_size, void* d_ws, size_t ws_size,
                              hipStream_t stream) {
    const float* x    = (const float*)d_in[0];
    const float* W1_l = (const float*)d_in[1];
    const float* b1   = (const float*)d_in[2];
    const float* W1_r = (const float*)d_in[3];
    const float* W2_l = (const float*)d_in[4];
    const float* b2   = (const float*)d_in[5];
    const float* W2_r = (const float*)d_in[6];
    const void*  ei   = d_in[7];
    float* out = (float*)d_out;

    const int N = in_sizes[0] / 128;      // 100000
    const int E = in_sizes[7] / 2;        // 1600000
    const int nbuck = (N + 127) >> 7;     // 782

    // workspace layout (~86 MB)
    uintptr_t base = (uintptr_t)d_ws;
    int* bucket_pos = (int*)(base + 64);                      // nbuck ints
    int* dhist = (int*)(base + 4096);                         // NBIN ints
    int* dcur  = (int*)(base + 4352);                         // NBIN ints
    int2* startcnt = (int2*)(base + 8192);                    // N int2
    int* csr = (int*)(((uintptr_t)(startcnt + N) + 255) & ~(uintptr_t)255); // nbuck*CAP
    uintptr_t p = ((uintptr_t)(csr + (size_t)nbuck * CAP) + 255) & ~(uintptr_t)255;
    unsigned short* xb    = (unsigned short*)p; p += (size_t)N * 128 * 2;   // bf16 x
    unsigned short* ebr   = (unsigned short*)p; p += (size_t)N * 128 * 2;   // ebuf region
    unsigned short* hbr   = (unsigned short*)p; p += (size_t)N * 128 * 2;   // z2 + nodeperm
    uint4* w1frag = (uint4*)p; p += 4096 * 16;
    uint4* w2frag = (uint4*)p; p += 2048 * 16;
    unsigned* ebuf = (unsigned*)ebr;       // nbuck*CAP uints
    unsigned short* z2 = hbr;              // bf16 N*64 (first half of hbr)
    int* nodeperm = (int*)(hbr + (size_t)N * 64);   // N ints (second half of hbr)

    const int* ei32 = (const int*)ei;
    const long long* ei64 = (const long long*)ei;

    // zero bucket counters + degree hist + degree cursors
    hipMemsetAsync((void*)base, 0, 8192, stream);

    long long n8 = (long long)N * 128 / 8;
    int ncvt = (int)((n8 + 255) / 256);
    int ept = (E + P2B * 256 - 1) / (P2B * 256);   // 13 for E=1.6M (<= MAXEPT)

    // fused front: pass2 sorted-partition | cvt | w frags
    fused_front<<<P2B + ncvt + 24, 256, 0, stream>>>(
        x, xb, n8, ncvt, W1_l, W1_r, w1frag, W2_l, W2_r, w2frag,
        ei32, ei64, E, ept, nbuck, N, bucket_pos, ebuf);

    pass3_finalize<<<nbuck, 256, 0, stream>>>(ebuf, bucket_pos, nbuck, N,
                                              startcnt, csr, dhist);

    // degree-balanced node permutation (counting sort, 64 bins)
    int pblocks = (N + 1023) / 1024;
    build_perm<<<pblocks, 256, 0, stream>>>(startcnt, dhist, dcur, nodeperm, N);

    // merged: 16-node agg (degree-balanced) + in-block gemm1+gemm2
    int gblocks = (N + 15) / 16;   // 6250, exact
    agg16_gemm<<<gblocks, 1024, 0, stream>>>(xb, startcnt, csr, nodeperm,
                                             w1frag, w2frag, b1, b2,
                                             z2, out, N);

    // layer 2 agg (commuted, dual-node waves) + in-place epilogue on out
    int a64blocks = (N + 7) / 8;
    agg_mean64_bf_ep<<<a64blocks, 256, 0, stream>>>(z2, startcnt, csr, out, N);
}

// Round 12
// 264.177 us; speedup vs baseline: 1.0959x; 1.0959x over previous
//
#include <hip/hip_runtime.h>
#include <hip/hip_bf16.h>
#include <cstdint>

// GraphSAGE 2-layer, bf16 features + fp32 accumulate, MFMA GEMMs.
// Layer1: h   = relu([mean_agg(x) | x] @ [W1_l; W1_r] + b1)   (K=256 MFMA GEMM)
// Layer2: out = mean_agg(h @ W2_l) + h @ W2_r + b2            (agg commutes w/ linear)
// R22 == R21 RESUBMIT (R11 bench was an infra failure: "container failed
// twice" — no kernel evidence; do not conflate infra retry with experiment).
// R21 pipeline (6 dispatches) — R17 restored (best verified, 266.6us):
//   memset(bucket_pos) -> fused_front (pass2 sorted-partition | cvt | wfrags)
//   -> pass3 -> agg_mean128 -> gemm12 (R12 dual-tile) -> agg64 (dual-node,
//   4-DEEP gather pipeline)
// R21 delta vs R17: agg64 main loop 2->4 outstanding row-gathers (j+=16).
// Mechanism: agg64 ran 2.7-3.0TB/s vs the proven 3.5TB/s path ceiling
// (agg128) with only 256B/wave in flight; 4-deep doubles in-flight bytes to
// match agg128's margin. Same mechanism as R17's dual-node win (-4.2us).
// MERGE AXIS CLOSED (R18/R19/R20 all FALSIFIED):
//   R18 per-block __threadfence handoff = L2 wbl2/inv flush -> 2880us. NEVER.
//   R19 16-wave barrier merge = 99.6us vs 92 split (half-idle gemm waves).
//   R20 degree-balance perm = 106.4us (+10MB fetch, locality loss; straggler
//   theory FALSIFIED — balancing saved nothing).
// Also FALSIFIED: R10 dim-slab, R11 shfl-bcast, R13 per-bucket serial agg,
// R14 16row gemm standalone, R15 range split. fdot2_f32_bf16 WRONG (R6).
// LEDGER: agg128 59 = fabric floor (177.8MB @3.5TB/s; schedule-insensitive);
// agg64 41 -> target ~37; gemm ~33; pass3 ~8; front ~30-40; ~60-80us fixed
// harness overhead (~30 reset dispatches/iter) untouchable.
// NOTE: R8: 113KB LDS -> 1 block/CU latency-bound. Keep gemm LDS small.

typedef __bf16 bf16x8 __attribute__((ext_vector_type(8)));
typedef float f32x4 __attribute__((ext_vector_type(4)));
typedef float f32x2 __attribute__((ext_vector_type(2)));

#define MAXBUCK 800   // >= ceil(102400/128)
#define CAP 2560      // per-bucket edge capacity; mean 2046, sigma ~45
#define MAXEPT 16
#define P2B 512       // pass2 blocks
#define P2E (MAXEPT * 256)   // staging capacity (4096; ept=13 uses 3328)
#define HSTRIDE 136   // bf16 elems per scratch row (272B, 16B-aligned)

__device__ __forceinline__ unsigned short f2bf(float f) {
    union { float f; unsigned int u; } v; v.f = f;
    unsigned int u = v.u;
    unsigned int r = ((u >> 16) & 1u) + 0x7fffu;
    return (unsigned short)((u + r) >> 16);
}

// unpack uint (2 bf16) -> f32x2 {lo, hi}
__device__ __forceinline__ f32x2 up2(unsigned int u) {
    uint2 t; t.x = u << 16; t.y = u & 0xffff0000u;
    return __builtin_bit_cast(f32x2, t);
}
__device__ __forceinline__ void accp(const uint4& v, f32x2* a) {
    a[0] += up2(v.x);
    a[1] += up2(v.y);
    a[2] += up2(v.z);
    a[3] += up2(v.w);
}
__device__ __forceinline__ void accpw(const uint4& v, float w, f32x2* a) {
    a[0] += up2(v.x) * w;
    a[1] += up2(v.y) * w;
    a[2] += up2(v.z) * w;
    a[3] += up2(v.w) * w;
}

__device__ __forceinline__ int edge_val(const int* ei32, const long long* ei64,
                                        int is64, size_t idx) {
    return is64 ? (int)ei64[idx] : ei32[idx];
}

// ---------------- FUSED FRONT: pass2 sorted-partition | cvt | w frags ------
__global__ __launch_bounds__(256) void fused_front(const float* __restrict__ x,
                                                   unsigned short* __restrict__ xb,
                                                   long long n8, int ncvt,
                                                   const float* __restrict__ W1l,
                                                   const float* __restrict__ W1r,
                                                   uint4* __restrict__ w1frag,
                                                   const float* __restrict__ W2l,
                                                   const float* __restrict__ W2r,
                                                   uint4* __restrict__ w2frag,
                                                   const int* __restrict__ ei32,
                                                   const long long* __restrict__ ei64,
                                                   int E, int ept, int nbuck,
                                                   int n_nodes,
                                                   int* __restrict__ bucket_pos,
                                                   unsigned* __restrict__ ebuf) {
    __shared__ int lhist[MAXBUCK];
    __shared__ int lexcl[MAXBUCK];
    __shared__ int gbase[MAXBUCK];
    __shared__ int part[256];
    __shared__ unsigned estage[P2E];
    __shared__ unsigned short bstage[P2E];
    int b = blockIdx.x;
    int t = threadIdx.x;
    if (b < P2B) {
        // ---- pass2 role: partition edges into padded buckets, sorted ----
        for (int i = t; i < nbuck; i += 256) lhist[i] = 0;
        __syncthreads();
        int is64;
        {   // self-detect: 8 uniform loads; garbage-as-int64 fails bounds
            int ok = 1;
            for (int i = 0; i < 8; ++i) {
                long long v = ei64[i];
                if (v < 0 || v >= n_nodes) ok = 0;
            }
            is64 = ok;
        }
        int base_e = b * (ept * 256);
        unsigned ed[MAXEPT];
        int bidx[MAXEPT];
        int slot[MAXEPT];
#pragma unroll 4
        for (int i = 0; i < ept; ++i) {
            int e = base_e + i * 256 + t;
            if (e < E) {
                int s = edge_val(ei32, ei64, is64, (size_t)e);
                int d = edge_val(ei32, ei64, is64, (size_t)E + e);
                ed[i] = ((unsigned)s << 7) | (unsigned)(d & 127);
                bidx[i] = d >> 7;
                slot[i] = atomicAdd(&lhist[d >> 7], 1);
            } else {
                slot[i] = -1;
            }
        }
        __syncthreads();
        // block-local exclusive scan of lhist[0..nbuck) (4 buckets/thread)
        int base4 = t * 4;
        int c0 = (base4 + 0 < nbuck) ? lhist[base4 + 0] : 0;
        int c1 = (base4 + 1 < nbuck) ? lhist[base4 + 1] : 0;
        int c2 = (base4 + 2 < nbuck) ? lhist[base4 + 2] : 0;
        int c3 = (base4 + 3 < nbuck) ? lhist[base4 + 3] : 0;
        int lsum = c0 + c1 + c2 + c3;
        part[t] = lsum;
        __syncthreads();
        for (int o = 1; o < 256; o <<= 1) {
            int xv = 0;
            if (t >= o) xv = part[t - o];
            __syncthreads();
            if (t >= o) part[t] += xv;
            __syncthreads();
        }
        {
            int run = part[t] - lsum;
            if (base4 + 0 < nbuck) { lexcl[base4 + 0] = run; run += c0; }
            if (base4 + 1 < nbuck) { lexcl[base4 + 1] = run; run += c1; }
            if (base4 + 2 < nbuck) { lexcl[base4 + 2] = run; run += c2; }
            if (base4 + 3 < nbuck) { lexcl[base4 + 3] = run; run += c3; }
        }
        // global reservations (independent of scan results)
        for (int i = t; i < nbuck; i += 256) {
            int c = lhist[i];
            gbase[i] = c ? atomicAdd(&bucket_pos[i], c) : 0;
        }
        __syncthreads();
        // stage edges into LDS, bucket-sorted
#pragma unroll 4
        for (int i = 0; i < ept; ++i) {
            if (slot[i] >= 0) {
                int pos = lexcl[bidx[i]] + slot[i];
                estage[pos] = ed[i];
                bstage[pos] = (unsigned short)bidx[i];
            }
        }
        __syncthreads();
        // emit: consecutive lanes -> same-bucket runs (coalesced-ish writes)
        int m_blk = E - base_e;
        if (m_blk < 0) m_blk = 0;
        if (m_blk > ept * 256) m_blk = ept * 256;
        for (int s = t; s < m_blk; s += 256) {
            int bb = bstage[s];
            int pos = gbase[bb] + (s - lexcl[bb]);
            if (pos < CAP) ebuf[(size_t)bb * CAP + pos] = estage[s];
        }
        return;
    }
    int cb = b - P2B;
    if (cb < ncvt) {
        // ---- cvt role: x (f32) -> xb (bf16), 16B out per thread ----
        long long i = (long long)cb * 256 + t;
        if (i >= n8) return;
        const float4* p = (const float4*)(x + i * 8);
        float4 a = p[0], c = p[1];
        uint4 o;
        o.x = (unsigned)f2bf(a.x) | ((unsigned)f2bf(a.y) << 16);
        o.y = (unsigned)f2bf(a.z) | ((unsigned)f2bf(a.w) << 16);
        o.z = (unsigned)f2bf(c.x) | ((unsigned)f2bf(c.y) << 16);
        o.w = (unsigned)f2bf(c.z) | ((unsigned)f2bf(c.w) << 16);
        ((uint4*)(xb))[i] = o;
        return;
    }
    if (cb < ncvt + 16) {   // W1 frags: Wcat[256][128] = [W1_l; W1_r], 64 frags
        int tid = (cb - ncvt) * 256 + t;   // 4096
        int fi = tid >> 6, lane = tid & 63;
        int ct = fi >> 3, ks = fi & 7;
        int k0 = ks * 32 + (lane >> 4) * 8;
        int n = ct * 16 + (lane & 15);
        unsigned short e[8];
#pragma unroll
        for (int j = 0; j < 8; ++j) {
            int k = k0 + j;
            float v = (k < 128) ? W1l[k * 128 + n] : W1r[(k - 128) * 128 + n];
            e[j] = f2bf(v);
        }
        uint4 o;
        o.x = (unsigned)e[0] | ((unsigned)e[1] << 16);
        o.y = (unsigned)e[2] | ((unsigned)e[3] << 16);
        o.z = (unsigned)e[4] | ((unsigned)e[5] << 16);
        o.w = (unsigned)e[6] | ((unsigned)e[7] << 16);
        w1frag[tid] = o;
        return;
    }
    // W2 frags: Wcat2[128][128] = [W2_l | W2_r], 32 frags
    int tid = (cb - ncvt - 16) * 256 + t;   // 2048
    if (tid >= 2048) return;
    int fi = tid >> 6, lane = tid & 63;
    int ct = fi >> 2, ks = fi & 3;
    int k0 = ks * 32 + (lane >> 4) * 8;
    int n = ct * 16 + (lane & 15);
    unsigned short e[8];
#pragma unroll
    for (int j = 0; j < 8; ++j) {
        int k = k0 + j;
        float v = (n < 64) ? W2l[k * 64 + n] : W2r[k * 64 + (n - 64)];
        e[j] = f2bf(v);
    }
    uint4 o;
    o.x = (unsigned)e[0] | ((unsigned)e[1] << 16);
    o.y = (unsigned)e[2] | ((unsigned)e[3] << 16);
    o.z = (unsigned)e[4] | ((unsigned)e[5] << 16);
    o.w = (unsigned)e[6] | ((unsigned)e[7] << 16);
    w2frag[tid] = o;
}

// pass3: one block per bucket (128 nodes); counts, scan, startcnt + csr
__global__ __launch_bounds__(256) void pass3_finalize(const unsigned* __restrict__ ebuf,
                                                      const int* __restrict__ bucket_pos,
                                                      int nbuck, int N,
                                                      int2* __restrict__ startcnt,
                                                      int* __restrict__ csr) {
    __shared__ int lcnt[128];
    __shared__ int lexcl[128];
    __shared__ int sc[128];
    int b = blockIdx.x;
    int t = threadIdx.x;
    int d0 = b << 7;
    int nb = N - d0; if (nb > 128) nb = 128;
    int m = bucket_pos[b]; if (m > CAP) m = CAP;
    const unsigned* eb = ebuf + (size_t)b * CAP;

    if (t < 128) lcnt[t] = 0;
    __syncthreads();
    for (int j = t; j < m; j += 256) {
        atomicAdd(&lcnt[eb[j] & 127u], 1);
    }
    __syncthreads();
    int v = 0;
    if (t < 128) { v = lcnt[t]; sc[t] = v; }
    __syncthreads();
    for (int o = 1; o < 128; o <<= 1) {
        int x = 0;
        if (t < 128 && t >= o) x = sc[t - o];
        __syncthreads();
        if (t < 128 && t >= o) sc[t] += x;
        __syncthreads();
    }
    if (t < 128) {
        int excl = sc[t] - v;
        lexcl[t] = excl;
        if (t < nb) startcnt[d0 + t] = make_int2(b * CAP + excl, v);
        lcnt[t] = 0;   // reuse as running pos
    }
    __syncthreads();
    for (int j = t; j < m; j += 256) {
        unsigned ed = eb[j];
        int li = (int)(ed & 127u);
        int slot = atomicAdd(&lcnt[li], 1);
        csr[b * CAP + lexcl[li] + slot] = (int)(ed >> 7);
    }
}

// ---------------- mean aggregation, D=128 bf16, 16B/lane ----------------
__global__ __launch_bounds__(256) void agg_mean128_bf(const unsigned short* __restrict__ Xb,
                                                      const int2* __restrict__ startcnt,
                                                      const int* __restrict__ csr,
                                                      unsigned short* __restrict__ outb,
                                                      int n_nodes) {
    int node = blockIdx.x * 4 + (threadIdx.x >> 6);
    if (node >= n_nodes) return;
    int lane = threadIdx.x & 63;
    int quad = lane >> 4;
    int l16 = lane & 15;
    int2 sc2 = startcnt[node];
    int s0 = sc2.x, deg = sc2.y, s1 = s0 + deg;
    f32x2 A0[4], A1[4];
#pragma unroll
    for (int k = 0; k < 4; ++k) { A0[k] = (f32x2){0.f, 0.f}; A1[k] = (f32x2){0.f, 0.f}; }
    int j = s0;
    for (; j + 8 <= s1; j += 8) {
        int p0 = csr[j + quad];
        int p1 = csr[j + 4 + quad];
        uint4 v0 = ((const uint4*)(Xb + (size_t)p0 * 128))[l16];
        uint4 v1 = ((const uint4*)(Xb + (size_t)p1 * 128))[l16];
        accp(v0, A0);
        accp(v1, A1);
    }
    if (j + 4 <= s1) {
        int p = csr[j + quad];
        uint4 v = ((const uint4*)(Xb + (size_t)p * 128))[l16];
        accp(v, A0);
        j += 4;
    }
    if (j < s1) {  // masked tail, 1..3 edges
        int jj = j + quad;
        int p = csr[(jj < s1) ? jj : (s1 - 1)];
        float w = (jj < s1) ? 1.0f : 0.0f;
        uint4 v = ((const uint4*)(Xb + (size_t)p * 128))[l16];
        accpw(v, w, A1);
    }
    float r[8];
#pragma unroll
    for (int k = 0; k < 4; ++k) {
        f32x2 s = A0[k] + A1[k];
        r[2 * k] = s.x;
        r[2 * k + 1] = s.y;
    }
#pragma unroll
    for (int k = 0; k < 8; ++k) r[k] += __shfl(r[k], lane ^ 16);
#pragma unroll
    for (int k = 0; k < 8; ++k) r[k] += __shfl(r[k], lane ^ 32);
    float inv = (deg > 0) ? 1.0f / (float)deg : 0.0f;
    if (quad == 0) {
        uint4 o;
        o.x = (unsigned)f2bf(r[0] * inv) | ((unsigned)f2bf(r[1] * inv) << 16);
        o.y = (unsigned)f2bf(r[2] * inv) | ((unsigned)f2bf(r[3] * inv) << 16);
        o.z = (unsigned)f2bf(r[4] * inv) | ((unsigned)f2bf(r[5] * inv) << 16);
        o.w = (unsigned)f2bf(r[6] * inv) | ((unsigned)f2bf(r[7] * inv) << 16);
        ((uint4*)(outb + (size_t)node * 128))[l16] = o;
    }
}

// ------- mean aggregation, D=64 bf16, DUAL-NODE waves, 4-deep, +w2 --------
// R17: 2 nodes per wave (lanes 0-31 / 32-63), 4 octs per half.
// R21: main loop 4 outstanding row-gathers (j+=16) — 512B/wave in flight.
__global__ __launch_bounds__(256) void agg_mean64_bf_ep(const unsigned short* __restrict__ Zb,
                                                        const float* __restrict__ Wadd,
                                                        const int2* __restrict__ startcnt,
                                                        const int* __restrict__ csr,
                                                        float* __restrict__ out,
                                                        int n_nodes) {
    int node = blockIdx.x * 8 + (threadIdx.x >> 5);   // 8 nodes per block
    if (node >= n_nodes) return;
    int lane = threadIdx.x & 63;
    int hl = lane & 31;          // lane within half
    int oct4 = hl >> 3;          // 0..3
    int l8 = hl & 7;
    int2 sc2 = startcnt[node];
    int s0 = sc2.x, deg = sc2.y, s1 = s0 + deg;
    f32x2 A0[4], A1[4];
#pragma unroll
    for (int k = 0; k < 4; ++k) { A0[k] = (f32x2){0.f, 0.f}; A1[k] = (f32x2){0.f, 0.f}; }
    int j = s0;
    for (; j + 16 <= s1; j += 16) {       // 4 gathers in flight
        int p0 = csr[j + oct4];
        int p1 = csr[j + 4 + oct4];
        int p2 = csr[j + 8 + oct4];
        int p3 = csr[j + 12 + oct4];
        uint4 v0 = ((const uint4*)(Zb + (size_t)p0 * 64))[l8];
        uint4 v1 = ((const uint4*)(Zb + (size_t)p1 * 64))[l8];
        uint4 v2 = ((const uint4*)(Zb + (size_t)p2 * 64))[l8];
        uint4 v3 = ((const uint4*)(Zb + (size_t)p3 * 64))[l8];
        accp(v0, A0);
        accp(v1, A1);
        accp(v2, A0);
        accp(v3, A1);
    }
    if (j + 8 <= s1) {                    // 2 gathers
        int p0 = csr[j + oct4];
        int p1 = csr[j + 4 + oct4];
        uint4 v0 = ((const uint4*)(Zb + (size_t)p0 * 64))[l8];
        uint4 v1 = ((const uint4*)(Zb + (size_t)p1 * 64))[l8];
        accp(v0, A0);
        accp(v1, A1);
        j += 8;
    }
    if (j + 4 <= s1) {
        int p = csr[j + oct4];
        uint4 v = ((const uint4*)(Zb + (size_t)p * 64))[l8];
        accp(v, A0);
        j += 4;
    }
    if (j < s1) {  // masked tail, 1..3 edges
        int jj = j + oct4;
        int p = csr[(jj < s1) ? jj : (s1 - 1)];
        float w = (jj < s1) ? 1.0f : 0.0f;
        uint4 v = ((const uint4*)(Zb + (size_t)p * 64))[l8];
        accpw(v, w, A1);
    }
    float r[8];
#pragma unroll
    for (int k = 0; k < 4; ++k) {
        f32x2 s = A0[k] + A1[k];
        r[2 * k] = s.x;
        r[2 * k + 1] = s.y;
    }
    // reduce across 4 octs within each 32-lane half (xor 8, 16 stay in-half)
#pragma unroll
    for (int k = 0; k < 8; ++k) r[k] += __shfl(r[k], lane ^ 8);
#pragma unroll
    for (int k = 0; k < 8; ++k) r[k] += __shfl(r[k], lane ^ 16);
    float inv = (deg > 0) ? 1.0f / (float)deg : 0.0f;
    if (oct4 == 0) {
        const float4* wp = (const float4*)(Wadd + (size_t)node * 64 + l8 * 8);
        float4 w0 = wp[0], w1 = wp[1];
        float4 o0, o1;
        o0.x = r[0] * inv + w0.x; o0.y = r[1] * inv + w0.y;
        o0.z = r[2] * inv + w0.z; o0.w = r[3] * inv + w0.w;
        o1.x = r[4] * inv + w1.x; o1.y = r[5] * inv + w1.y;
        o1.z = r[6] * inv + w1.z; o1.w = r[7] * inv + w1.w;
        float4* op = (float4*)(out + (size_t)node * 64 + l8 * 8);
        op[0] = o0; op[1] = o1;
    }
}

// ---------------- FUSED GEMM1+GEMM2 (MFMA), prefetched weight streams ------
// R12 version: one weight load -> two MFMAs (dual m-tile accs);
// 2-stage register prefetch (wc/wn). LDS = 4 x 8704B = 34.8KB; (256,3).
__global__ __launch_bounds__(256, 3) void gemm12_mfma(const unsigned short* __restrict__ meanb,
                                                      const unsigned short* __restrict__ xb,
                                                      const uint4* __restrict__ w1frag,
                                                      const uint4* __restrict__ w2frag,
                                                      const float* __restrict__ b1,
                                                      const float* __restrict__ b2,
                                                      unsigned short* __restrict__ z2,
                                                      float* __restrict__ w2out,
                                                      int nrows) {
    __shared__ unsigned short hs[4][32 * HSTRIDE]; // 34816 B
    const int wid = threadIdx.x >> 6, lane = threadIdx.x & 63;
    const int quad = lane >> 4, l16 = lane & 15;
    const int m0 = blockIdx.x * 128 + wid * 32;
    unsigned short* hsw = &hs[wid][0];
    const uint4* w1p = w1frag + lane;
    const uint4* w2p = w2frag + lane;

    // A-frags for both m-tiles
    bf16x8 af[2][8];
#pragma unroll
    for (int mt = 0; mt < 2; ++mt) {
        int row = m0 + mt * 16 + l16;
        int rowc = (row < nrows) ? row : (nrows - 1);
        const uint4* mrow = (const uint4*)(meanb + (size_t)rowc * 128);
        const uint4* xrow = (const uint4*)(xb + (size_t)rowc * 128);
#pragma unroll
        for (int ks = 0; ks < 4; ++ks) {
            af[mt][ks]     = __builtin_bit_cast(bf16x8, mrow[ks * 4 + quad]);
            af[mt][ks + 4] = __builtin_bit_cast(bf16x8, xrow[ks * 4 + quad]);
        }
    }

    // ---- gemm1: prefetched W1 stream, one load -> two MFMAs ----
    uint4 wc[8], wn[8];
#pragma unroll
    for (int ks = 0; ks < 8; ++ks) wc[ks] = w1p[ks * 64];
#pragma unroll
    for (int ct = 0; ct < 8; ++ct) {
        if (ct < 7) {
#pragma unroll
            for (int ks = 0; ks < 8; ++ks) wn[ks] = w1p[((ct + 1) * 8 + ks) * 64];
        }
        f32x4 a0 = (f32x4){0.f, 0.f, 0.f, 0.f};
        f32x4 a1 = (f32x4){0.f, 0.f, 0.f, 0.f};
#pragma unroll
        for (int ks = 0; ks < 8; ++ks) {
            bf16x8 bf = __builtin_bit_cast(bf16x8, wc[ks]);
            a0 = __builtin_amdgcn_mfma_f32_16x16x32_bf16(af[0][ks], bf, a0, 0, 0, 0);
            a1 = __builtin_amdgcn_mfma_f32_16x16x32_bf16(af[1][ks], bf, a1, 0, 0, 0);
        }
        int col = ct * 16 + l16;
        float bb = b1[col];
#pragma unroll
        for (int r = 0; r < 4; ++r) {
            hsw[(quad * 4 + r) * HSTRIDE + col] = f2bf(fmaxf(a0[r] + bb, 0.f));
            hsw[(16 + quad * 4 + r) * HSTRIDE + col] = f2bf(fmaxf(a1[r] + bb, 0.f));
        }
#pragma unroll
        for (int ks = 0; ks < 8; ++ks) wc[ks] = wn[ks];
    }

    // ---- transpose read: A-frags of h (row = l16 (+16), k = ks*32+quad*8+j)
    bf16x8 af2[2][4];
#pragma unroll
    for (int mt = 0; mt < 2; ++mt)
#pragma unroll
        for (int ks = 0; ks < 4; ++ks) {
            uint4 t = *(const uint4*)(hsw + (mt * 16 + l16) * HSTRIDE + ks * 32 + quad * 8);
            af2[mt][ks] = __builtin_bit_cast(bf16x8, t);
        }

    // ---- gemm2: prefetched W2 stream, one load -> two MFMAs ----
    uint4 wc2[4], wn2[4];
#pragma unroll
    for (int ks = 0; ks < 4; ++ks) wc2[ks] = w2p[ks * 64];
#pragma unroll
    for (int ct = 0; ct < 8; ++ct) {
        if (ct < 7) {
#pragma unroll
            for (int ks = 0; ks < 4; ++ks) wn2[ks] = w2p[((ct + 1) * 4 + ks) * 64];
        }
        f32x4 a0 = (f32x4){0.f, 0.f, 0.f, 0.f};
        f32x4 a1 = (f32x4){0.f, 0.f, 0.f, 0.f};
#pragma unroll
        for (int ks = 0; ks < 4; ++ks) {
            bf16x8 bf = __builtin_bit_cast(bf16x8, wc2[ks]);
            a0 = __builtin_amdgcn_mfma_f32_16x16x32_bf16(af2[0][ks], bf, a0, 0, 0, 0);
            a1 = __builtin_amdgcn_mfma_f32_16x16x32_bf16(af2[1][ks], bf, a1, 0, 0, 0);
        }
        int col = ct * 16 + l16;
#pragma unroll
        for (int mt = 0; mt < 2; ++mt) {
            f32x4 acc = mt ? a1 : a0;
#pragma unroll
            for (int r = 0; r < 4; ++r) {
                int orow = m0 + mt * 16 + quad * 4 + r;
                if (orow < nrows) {
                    if (col < 64) {
                        z2[(size_t)orow * 64 + col] = f2bf(acc[r]);
                    } else {
                        w2out[(size_t)orow * 64 + (col - 64)] = acc[r] + b2[col - 64];
                    }
                }
            }
        }
#pragma unroll
        for (int ks = 0; ks < 4; ++ks) wc2[ks] = wn2[ks];
    }
}

extern "C" void kernel_launch(void* const* d_in, const int* in_sizes, int n_in,
                              void* d_out, int out_size, void* d_ws, size_t ws_size,
                              hipStream_t stream) {
    const float* x    = (const float*)d_in[0];
    const float* W1_l = (const float*)d_in[1];
    const float* b1   = (const float*)d_in[2];
    const float* W1_r = (const float*)d_in[3];
    const float* W2_l = (const float*)d_in[4];
    const float* b2   = (const float*)d_in[5];
    const float* W2_r = (const float*)d_in[6];
    const void*  ei   = d_in[7];
    float* out = (float*)d_out;

    const int N = in_sizes[0] / 128;      // 100000
    const int E = in_sizes[7] / 2;        // 1600000
    const int nbuck = (N + 127) >> 7;     // 782

    // workspace layout (~86 MB)
    uintptr_t base = (uintptr_t)d_ws;
    int* bucket_pos = (int*)(base + 64);                      // nbuck
    int2* startcnt = (int2*)(base + 8192);                    // N int2
    int* csr = (int*)((uintptr_t)(startcnt + N) + 255 & ~(uintptr_t)255); // nbuck*CAP
    uintptr_t p = ((uintptr_t)(csr + (size_t)nbuck * CAP) + 255) & ~(uintptr_t)255;
    unsigned short* xb    = (unsigned short*)p; p += (size_t)N * 128 * 2;   // bf16 x / later w2 fp32
    unsigned short* meanb = (unsigned short*)p; p += (size_t)N * 128 * 2;   // ebuf / bf16 mean
    unsigned short* hbr   = (unsigned short*)p; p += (size_t)N * 128 * 2;   // z2 region
    uint4* w1frag = (uint4*)p; p += 4096 * 16;
    uint4* w2frag = (uint4*)p; p += 2048 * 16;
    unsigned* ebuf = (unsigned*)meanb;     // nbuck*CAP uints; dead before agg writes meanb
    unsigned short* z2 = hbr;              // bf16 N*64
    float* w2 = (float*)xb;                // fp32 N*64; wave reads its xb rows before
                                           // writing the same rows as w2 (1:1 overlap)

    const int* ei32 = (const int*)ei;
    const long long* ei64 = (const long long*)ei;

    // zero bucket counters (pass2 blocks self-detect edge dtype)
    hipMemsetAsync(bucket_pos, 0, (size_t)nbuck * sizeof(int), stream);

    long long n8 = (long long)N * 128 / 8;
    int ncvt = (int)((n8 + 255) / 256);
    int ept = (E + P2B * 256 - 1) / (P2B * 256);   // 13 for E=1.6M (<= MAXEPT)

    // fused front: pass2 sorted-partition | cvt | w frags
    fused_front<<<P2B + ncvt + 24, 256, 0, stream>>>(
        x, xb, n8, ncvt, W1_l, W1_r, w1frag, W2_l, W2_r, w2frag,
        ei32, ei64, E, ept, nbuck, N, bucket_pos, ebuf);

    pass3_finalize<<<nbuck, 256, 0, stream>>>(ebuf, bucket_pos, nbuck, N,
                                              startcnt, csr);

    int ablocks = (N + 3) / 4;
    int gblocks = (N + 127) / 128;

    // layer 1 agg
    agg_mean128_bf<<<ablocks, 256, 0, stream>>>(xb, startcnt, csr, meanb, N);
    // fused layer-1 linear + layer-2 linear (h stays on-chip)
    gemm12_mfma<<<gblocks, 256, 0, stream>>>(meanb, xb, w1frag, w2frag, b1, b2,
                                             z2, w2, N);
    // layer 2 agg (commuted, dual-node waves, 4-deep) + epilogue
    int a64blocks = (N + 7) / 8;
    agg_mean64_bf_ep<<<a64blocks, 256, 0, stream>>>(z2, w2, startcnt, csr, out, N);
}